// Round 17
// baseline (25.120 us; speedup 1.0000x reference)
//
#include <hip/hip_runtime.h>
#include <math.h>

#define KNN 8
#define QPB 16          // queries per block
#define SUB 16          // sub-lanes per query
#define BLK 256         // QPB*SUB threads, 4 waves
#define CAP 768         // staged rows (covers block's 1-2 batches)
#define PFU 9           // prefetch unroll: 9*256 >= 16*131 floats

// Single fused kernel, single dispatch, XCD-swizzled, whole-grid co-resident.
// R17 delta vs R16: bulk stripe prefetch. Each block streams its own 16 full
// x1 rows (coords+features, 2096 floats) as 9 independent coalesced dword
// loads per thread at kernel start; union over blocks = all of x1 exactly
// once, landing in the owning XCD's L2 (slab ~2.3MB < 4MB). The later stage
// and merge-gather phases then hit warm L2 instead of serialized cold-HBM
// demand misses. Values kept live via asm use after the scan (no DCE, no
// early waitcnt). Everything else identical to R16.
__launch_bounds__(BLK, 4)
__global__ void knn_one(const float* __restrict__ x1,
                        const float* __restrict__ x2,
                        const int* __restrict__ b1,
                        const int* __restrict__ b2,
                        int N, int ROW, float scale,
                        unsigned long long* __restrict__ slot,
                        float* __restrict__ out) {
  __shared__ float4 c4[CAP];          // {x, y, z, batch_id_bits}
  __shared__ int   s_info[2];         // block staging range {s1, e1}
  __shared__ float wred[BLK / 64];
  __shared__ float sm[BLK];           // finale tree

  // Bijective XCD swizzle: consecutive work-ids (same batch) share an XCD L2.
  const int nwg = (int)gridDim.x;
  const int xcd = (int)blockIdx.x & 7, pos = (int)blockIdx.x >> 3;
  const int q8 = nwg >> 3, r8 = nwg & 7;
  const int bid = (xcd < r8) ? xcd * (q8 + 1) + pos
                             : r8 * (q8 + 1) + (xcd - r8) * q8 + pos;

  const int tid  = threadIdx.x;
  const int lane = tid & 63;
  const int wv   = tid >> 6;          // 0..3
  const int qi   = tid >> 4;          // 0..15 query within block
  const int sub  = tid & (SUB - 1);   // lane in 16-group; owned dim base
  const int q0   = bid * QPB;
  const int q    = min(q0 + qi, N - 1);
  const int qlast = min(q0 + QPB - 1, N - 1);

  // --- Bulk stripe prefetch: 9 independent coalesced loads covering this
  // block's 16 full x1 rows. Issued first; consumed (asm) after the scan.
  float pv[PFU];
  {
    const float* base = x1 + (size_t)q0 * ROW;
    const int nfl = QPB * ROW;         // 2096 floats for ROW=131
#pragma unroll
    for (int u = 0; u < PFU; ++u) {
      int i = min(tid + u * BLK, nfl - 1);   // clamp: dup loads are harmless
      pv[u] = base[i];
    }
  }

  // Hoisted x2 reads: coords + this lane's 8 owned feature dims
  // (also fully primes x2: the 16 lanes x 8 taps cover the whole row).
  float qx, qy, qz; int mybatch;
  float f2v[KNN];
  {
    const float* c2 = x2 + (size_t)q * ROW;
    qx = c2[0]; qy = c2[1]; qz = c2[2];
    mybatch = b2[q];
    const float* f2 = c2 + 3 + sub;
#pragma unroll
    for (int t = 0; t < KNN; ++t) f2v[t] = f2[16 * t];
  }

  // Wave-cooperative lower_bound on b1 (64-way fanout, ~3 dependent rounds).
  if (wv < 2) {
    const int bb = (wv == 0) ? b2[q0] : b2[qlast];
    const int target = bb + wv;       // wv0: lb(b_first), wv1: lb(b_last+1)
    int lo = 0, hi = N;
    while (lo < hi) {
      int step = (hi - lo + 63) >> 6;
      int p = lo + lane * step;
      bool pred = (p < hi) && (b1[p] < target);
      int c = __popcll(__ballot(pred));
      if (c == 0) { hi = lo; break; }
      int nlo = lo + (c - 1) * step + 1;
      hi = min(hi, lo + c * step);
      lo = nlo;
    }
    if (lane == 0) s_info[wv] = lo;
  }

  // Sorted top-8 as packed keys: (float_bits(d) << 32) | idx.
  // d >= 0 -> bits monotone -> u64 order == lexicographic (d, idx) exactly.
  unsigned long long K[KNN];
  const unsigned long long KINIT = 0x7F800000ULL << 32;   // (inf, 0)
#pragma unroll
  for (int k = 0; k < KNN; ++k) K[k] = KINIT;

  __syncthreads();
  const int s1v = s_info[0], e1v = s_info[1];

  for (int t0 = s1v; t0 < e1v; t0 += CAP) {   // one tile in practice
    const int t1 = min(t0 + CAP, e1v);
    __syncthreads();
    for (int i = t0 + tid; i < t1; i += BLK) {
      const float* p = x1 + (size_t)i * ROW;
      c4[i - t0] = make_float4(p[0], p[1], p[2], __int_as_float(b1[i]));
    }
    __syncthreads();
    // All lanes scan the tile; foreign-batch rows masked to key=~0.
    for (int j = t0 + sub; j < t1; j += SUB) {
      float4 c = c4[j - t0];
      float dx = qx - c.x, dy = qy - c.y, dz = qz - c.z;
      float d = fmaf(dx, dx, fmaf(dy, dy, dz * dz));
      unsigned long long key =
          ((unsigned long long)__float_as_uint(d) << 32) | (unsigned)j;
      key = (__float_as_int(c.w) == mybatch) ? key : ~0ULL;
      // Branchless sorted insert (strict u64 < == lexicographic (d, idx)).
      bool lt[KNN];
#pragma unroll
      for (int k = 0; k < KNN; ++k) lt[k] = key < K[k];
#pragma unroll
      for (int k = KNN - 1; k > 0; --k)
        K[k] = lt[k - 1] ? K[k - 1] : (lt[k] ? key : K[k]);
      K[0] = lt[0] ? key : K[0];
    }
  }

  // Consume the prefetch (keeps loads live; waitcnt is free by now).
  {
    float ds = 0.f;
#pragma unroll
    for (int u = 0; u < PFU; ++u) ds += pv[u];
    asm volatile("" :: "v"(ds));
  }

  // Fused exact merge + gather (16-lane butterfly u64-min, pop, immediate
  // feature loads; rounds' loads pipeline; all rows L2-warm from prefetch).
  float acc[KNN];
#pragma unroll
  for (int t = 0; t < KNN; ++t) acc[t] = 0.f;
  float sw = 0.f;
  const float* x1f = x1 + 3 + sub;
#pragma unroll
  for (int r = 0; r < KNN; ++r) {
    unsigned long long h = K[0], b = h;
#pragma unroll
    for (int m = 1; m <= 8; m <<= 1) {
      unsigned long long o = __shfl_xor(b, m);
      b = (o < b) ? o : b;
    }
    if (h == b) {                 // pop winner; identical pads multi-pop harmlessly
#pragma unroll
      for (int k = 0; k < KNN - 1; ++k) K[k] = K[k + 1];
      K[KNN - 1] = KINIT;
    }
    float bd = __uint_as_float((unsigned)(b >> 32));
    int   bi = (int)(unsigned)b;
    float w = 1.0f / fmaxf(bd, 1e-16f);   // d=inf (pad) -> w = 0
    sw += w;
    const float* f = x1f + (size_t)bi * ROW;
#pragma unroll
    for (int t = 0; t < KNN; ++t) acc[t] = fmaf(w, f[16 * t], acc[t]);
  }

  // Epilogue: this lane's 8 dims of its query's squared error.
  float pacc = 0.0f;
  if (q0 + qi < N) {
    float rinv = 1.0f / sw;
#pragma unroll
    for (int t = 0; t < KNN; ++t) {
      float e = fmaf(acc[t], rinv, -f2v[t]);
      pacc += e * e;
    }
  }
#pragma unroll
  for (int off = 32; off > 0; off >>= 1) pacc += __shfl_xor(pacc, off);
  if (lane == 0) wred[wv] = pacc;
  __syncthreads();

  // Publish {TAG(bid) | partial} as one 64-bit agent-scope relaxed store.
  if (tid == 0) {
    float s = (wred[0] + wred[1]) + (wred[2] + wred[3]);
    unsigned long long v =
        ((unsigned long long)(0x5A000000u | (unsigned)bid) << 32) |
        (unsigned long long)__float_as_uint(s);
    __hip_atomic_store(&slot[bid], v, __ATOMIC_RELAXED,
                       __HIP_MEMORY_SCOPE_AGENT);
  }

  // Parallel finale (reader = work-block 0, ALL 256 threads): thread t owns
  // slots {t, t+256, t+512, t+768}; spins each (values deterministic => any
  // interleaving bit-identical), sums in fixed index order, fixed LDS tree.
  if (bid == 0) {
    float s = 0.0f;
    for (int rr = 0; rr * BLK + tid < nwg; ++rr) {
      int i = rr * BLK + tid;
      unsigned tag = 0x5A000000u | (unsigned)i;
      unsigned long long x = __hip_atomic_load(&slot[i], __ATOMIC_RELAXED,
                                               __HIP_MEMORY_SCOPE_AGENT);
      while ((unsigned)(x >> 32) != tag) {
        __builtin_amdgcn_s_sleep(2);
        x = __hip_atomic_load(&slot[i], __ATOMIC_RELAXED,
                              __HIP_MEMORY_SCOPE_AGENT);
      }
      s += __uint_as_float((unsigned)x);   // thread-local, fixed rr-order
    }
    sm[tid] = s;
    __syncthreads();
    for (int st = BLK / 2; st > 0; st >>= 1) {
      if (tid < st) sm[tid] += sm[tid + st];
      __syncthreads();
    }
    if (tid == 0) out[0] = sm[0] * scale;
  }
}

extern "C" void kernel_launch(void* const* d_in, const int* in_sizes, int n_in,
                              void* d_out, int out_size, void* d_ws, size_t ws_size,
                              hipStream_t stream) {
  const float* x1 = (const float*)d_in[0];
  const float* x2 = (const float*)d_in[1];
  const int* b1 = (const int*)d_in[2];
  const int* b2 = (const int*)d_in[3];
  int N = in_sizes[2];            // 16384
  int ROW = in_sizes[0] / N;      // 131
  float* out = (float*)d_out;

  int blocks = (N + QPB - 1) / QPB;              // 1024
  unsigned long long* slot = (unsigned long long*)d_ws;
  if (ws_size < (size_t)blocks * sizeof(unsigned long long)) return;

  float scale = 1.0f / ((float)N * (float)(ROW - 3));
  knn_one<<<blocks, BLK, 0, stream>>>(x1, x2, b1, b2, N, ROW, scale, slot, out);
}

// Round 18
// 24.653 us; speedup vs baseline: 1.0189x; 1.0189x over previous
//
#include <hip/hip_runtime.h>
#include <math.h>

#define KNN 8
#define QPB 32          // queries per block
#define SUB 16          // sub-lanes per query
#define BLK 512         // QPB*SUB threads, 8 waves
#define CAP 1024        // staged candidates per LDS tile

// Single fused kernel, single dispatch, XCD-swizzled (R12 skeleton).
// R13 (best measured, 24.64us): (1) all x2 reads (coords + the 8 feature
// dims this lane owns) hoisted to kernel start -> ~11 independent loads in
// flight from t=0, overlapping search/stage/scan; (2) the feature gather is
// fused into the merge: each popped winner's row loads issue immediately,
// so all 8 rounds' misses pipeline.
__launch_bounds__(BLK, 4)
__global__ void knn_one(const float* __restrict__ x1,
                        const float* __restrict__ x2,
                        const int* __restrict__ b1,
                        const int* __restrict__ b2,
                        int N, int ROW, float scale,
                        unsigned long long* __restrict__ slot,
                        float* __restrict__ out) {
  __shared__ float4 c4[CAP];          // {x, y, z, |c|^2}
  __shared__ int   bs[CAP];           // batch id per staged row
  __shared__ int   s_info[2];         // block staging range {s1, e1}
  __shared__ float wred[BLK / 64];

  // Bijective XCD swizzle: consecutive work-ids (same batch) share an XCD L2.
  const int nwg = (int)gridDim.x;
  const int xcd = (int)blockIdx.x & 7, pos = (int)blockIdx.x >> 3;
  const int q8 = nwg >> 3, r8 = nwg & 7;
  const int bid = (xcd < r8) ? xcd * (q8 + 1) + pos
                             : r8 * (q8 + 1) + (xcd - r8) * q8 + pos;

  const int tid  = threadIdx.x;
  const int lane = tid & 63;
  const int wv   = tid >> 6;          // 0..7
  const int qi   = tid >> 4;          // 0..31 query within block
  const int sub  = tid & (SUB - 1);   // lane in 16-group; owned dim base
  const int q0   = bid * QPB;
  const int q    = min(q0 + qi, N - 1);
  const int qlast = min(q0 + QPB - 1, N - 1);

  // Hoisted x2 reads: query coords + this lane's 8 owned feature dims
  // (f2v consumed only in the epilogue -> pure prefetch overlap).
  float qx, qy, qz; int mybatch;
  float f2v[KNN];
  {
    const float* c2 = x2 + (size_t)q * ROW;
    qx = c2[0]; qy = c2[1]; qz = c2[2];
    mybatch = b2[q];
    const float* f2 = c2 + 3 + sub;
#pragma unroll
    for (int t = 0; t < KNN; ++t) f2v[t] = f2[16 * t];
  }
  const float n2 = qx * qx + qy * qy + qz * qz;

  // Wave-cooperative lower_bound on b1 (64-way fanout). Invariant: lb in [lo,hi].
  if (wv < 2) {
    const int bb = (wv == 0) ? b2[q0] : b2[qlast];
    const int target = bb + wv;       // wv0: lb(b_first), wv1: lb(b_last+1)
    int lo = 0, hi = N;
    while (lo < hi) {
      int step = (hi - lo + 63) >> 6;
      int p = lo + lane * step;
      bool pred = (p < hi) && (b1[p] < target);
      int c = __popcll(__ballot(pred));
      if (c == 0) { hi = lo; break; }
      int nlo = lo + (c - 1) * step + 1;
      hi = min(hi, lo + c * step);
      lo = nlo;
    }
    if (lane == 0) s_info[wv] = lo;
  }

  float dist[KNN]; int nidx[KNN];
#pragma unroll
  for (int k = 0; k < KNN; ++k) { dist[k] = INFINITY; nidx[k] = 0; }

  __syncthreads();
  const int s1v = s_info[0], e1v = s_info[1];

  for (int t0 = s1v; t0 < e1v; t0 += CAP) {
    const int t1 = min(t0 + CAP, e1v);
    __syncthreads();                   // c4/bs reuse guard (uniform trip count)
    for (int i = t0 + tid; i < t1; i += BLK) {
      const float* p = x1 + (size_t)i * ROW;
      float cx = p[0], cy = p[1], cz = p[2];
      c4[i - t0] = make_float4(cx, cy, cz, cx * cx + cy * cy + cz * cz);
      bs[i - t0] = b1[i];
    }
    __syncthreads();
    // All lanes scan the whole tile; foreign-batch rows masked to INF.
    for (int j = t0 + sub; j < t1; j += SUB) {
      float4 c = c4[j - t0];
      int bv = bs[j - t0];
      float d = fmaxf(fmaf(-2.0f, fmaf(qx, c.x, fmaf(qy, c.y, qz * c.z)), n2 + c.w), 0.0f);
      d = (bv == mybatch) ? d : INFINITY;
      // Branchless sorted insert, strict < (ascending j => per-lane ties keep
      // the earlier index, matching jax.lax.top_k).
      bool lt[KNN];
#pragma unroll
      for (int k = 0; k < KNN; ++k) lt[k] = d < dist[k];
#pragma unroll
      for (int k = KNN - 1; k > 0; --k) {
        dist[k] = lt[k - 1] ? dist[k - 1] : (lt[k] ? d : dist[k]);
        nidx[k] = lt[k - 1] ? nidx[k - 1] : (lt[k] ? j : nidx[k]);
      }
      dist[0] = lt[0] ? d : dist[0];
      nidx[0] = lt[0] ? j : nidx[0];
    }
  }

  // Fused exact merge + gather. Round r: lexicographic (d, idx) min across
  // the 16-lane group (butterfly => converged in every lane); pop the owner;
  // every lane immediately issues that row's loads for its 8 owned dims.
  // Rounds' loads pipeline (next round's shfls don't depend on them).
  // Padded (inf,0) entries: w=0, row 0 loaded harmlessly, acc += 0.
  float acc[KNN];
#pragma unroll
  for (int t = 0; t < KNN; ++t) acc[t] = 0.f;
  float sw = 0.f;
  const float* x1f = x1 + 3 + sub;
#pragma unroll
  for (int r = 0; r < KNN; ++r) {
    float hd = dist[0]; int hx = nidx[0];
    float bd = hd; int bi = hx;
#pragma unroll
    for (int m = 1; m <= 8; m <<= 1) {
      float od = __shfl_xor(bd, m); int oi = __shfl_xor(bi, m);
      if (od < bd || (od == bd && oi < bi)) { bd = od; bi = oi; }
    }
    if (hd == bd && hx == bi) {   // pop winner; (inf,0) pads multi-pop harmlessly
#pragma unroll
      for (int k = 0; k < KNN - 1; ++k) { dist[k] = dist[k + 1]; nidx[k] = nidx[k + 1]; }
      dist[KNN - 1] = INFINITY; nidx[KNN - 1] = 0;
    }
    float w = 1.0f / fmaxf(bd, 1e-16f);   // d=inf (pad) -> w = 0
    sw += w;
    const float* f = x1f + (size_t)bi * ROW;
#pragma unroll
    for (int t = 0; t < KNN; ++t) acc[t] = fmaf(w, f[16 * t], acc[t]);
  }

  // Epilogue: this lane's 8 dims of its query's squared error.
  float pacc = 0.0f;
  if (q0 + qi < N) {
    float rinv = 1.0f / sw;
#pragma unroll
    for (int t = 0; t < KNN; ++t) {
      float e = fmaf(acc[t], rinv, -f2v[t]);
      pacc += e * e;
    }
  }
  // Wave sum: the 4 groups of a wave hold disjoint dims of 4 queries.
#pragma unroll
  for (int off = 32; off > 0; off >>= 1) pacc += __shfl_xor(pacc, off);
  if (lane == 0) wred[wv] = pacc;
  __syncthreads();

  // Publish {TAG(bid) | partial} as one 64-bit agent-scope relaxed store.
  if (tid == 0) {
    float s = 0.0f;
#pragma unroll
    for (int w = 0; w < BLK / 64; ++w) s += wred[w];
    unsigned long long v =
        ((unsigned long long)(0x5A000000u | (unsigned)bid) << 32) |
        (unsigned long long)__float_as_uint(s);
    __hip_atomic_store(&slot[bid], v, __ATOMIC_RELAXED,
                       __HIP_MEMORY_SCOPE_AGENT);
  }

  // Work-block 0 / wave 0: spin-read all slots (deterministic values => any
  // interleaving is bit-identical), fixed-order sum, write result.
  if (bid == 0 && wv == 0) {
    float s = 0.0f;
    for (int r = 0; r * 64 + lane < nwg; ++r) {
      int i = r * 64 + lane;
      unsigned tag = 0x5A000000u | (unsigned)i;
      unsigned long long x = __hip_atomic_load(&slot[i], __ATOMIC_RELAXED,
                                               __HIP_MEMORY_SCOPE_AGENT);
      while ((unsigned)(x >> 32) != tag) {
        __builtin_amdgcn_s_sleep(8);
        x = __hip_atomic_load(&slot[i], __ATOMIC_RELAXED,
                              __HIP_MEMORY_SCOPE_AGENT);
      }
      s += __uint_as_float((unsigned)x);   // lane-local, fixed r-order
    }
#pragma unroll
    for (int off = 32; off > 0; off >>= 1) s += __shfl_xor(s, off);
    if (lane == 0) out[0] = s * scale;
  }
}

extern "C" void kernel_launch(void* const* d_in, const int* in_sizes, int n_in,
                              void* d_out, int out_size, void* d_ws, size_t ws_size,
                              hipStream_t stream) {
  const float* x1 = (const float*)d_in[0];
  const float* x2 = (const float*)d_in[1];
  const int* b1 = (const int*)d_in[2];
  const int* b2 = (const int*)d_in[3];
  int N = in_sizes[2];            // 16384
  int ROW = in_sizes[0] / N;      // 131
  float* out = (float*)d_out;

  int blocks = (N + QPB - 1) / QPB;              // 512
  unsigned long long* slot = (unsigned long long*)d_ws;
  if (ws_size < (size_t)blocks * sizeof(unsigned long long)) return;

  float scale = 1.0f / ((float)N * (float)(ROW - 3));
  knn_one<<<blocks, BLK, 0, stream>>>(x1, x2, b1, b2, N, ROW, scale, slot, out);
}